// Round 2
// baseline (21384.048 us; speedup 1.0000x reference)
//
#include <hip/hip_runtime.h>
#include <math.h>

#define Bb    32
#define Nn    4096
#define HISTC 16
#define PREDC 8
#define TTC   24
#define EC    65536
#define BN    (Bb*Nn)          // 131072
#define WT_STRIDE 36           // 144B row stride: 16B aligned
#define GEX_STRIDE 148
#define SH_STRIDE 36

__device__ __forceinline__ float sigm(float x){ return 1.f/(1.f+expf(-x)); }

// ---------------- CSR build ----------------
__global__ void k_deg(const int* __restrict__ ei, int* deg, int* cnt){
  int e = blockIdx.x*blockDim.x + threadIdx.x;
  if (e < EC){ atomicAdd(&deg[ei[e]],1); atomicAdd(&cnt[ei[EC+e]],1); }
}
__global__ void k_dis(const int* __restrict__ deg, float* dis){
  int n = blockIdx.x*blockDim.x + threadIdx.x;
  if (n < Nn) dis[n] = deg[n] > 0 ? rsqrtf((float)deg[n]) : 0.f;
}
__global__ void k_scan(const int* __restrict__ cnt, int* ptr){
  __shared__ int sd[1024];
  int t = threadIdx.x;
  int c0=cnt[4*t], c1=cnt[4*t+1], c2=cnt[4*t+2], c3=cnt[4*t+3];
  int s = c0+c1+c2+c3;
  sd[t] = s; __syncthreads();
  for (int off=1; off<1024; off<<=1){
    int v = (t>=off) ? sd[t-off] : 0;
    __syncthreads();
    sd[t] += v;
    __syncthreads();
  }
  int excl = sd[t]-s;
  ptr[4*t]=excl; ptr[4*t+1]=excl+c0; ptr[4*t+2]=excl+c0+c1; ptr[4*t+3]=excl+c0+c1+c2;
  if (t==1023) ptr[4096]=sd[1023];
}
__global__ void k_fill(const int* __restrict__ ei, const float* __restrict__ dis,
                       const int* __restrict__ ptr, int* fillc, int* csrc, float* cnrm){
  int e = blockIdx.x*blockDim.x + threadIdx.x;
  if (e < EC){
    int s = ei[e], d = ei[EC+e];
    int pos = ptr[d] + atomicAdd(&fillc[d],1);
    csrc[pos] = s;
    cnrm[pos] = -dis[s]*dis[d];
  }
}

// ---------------- fused z-compute + LDS gather + sigmoid : history ----------------
// one block per (t,b) slice; z for all 4096 nodes in LDS, gather from LDS
__global__ __launch_bounds__(1024)
void k_xg_hist(const float* __restrict__ pm25, const float* __restrict__ feat,
               const float* __restrict__ cw, const float* __restrict__ cb,
               const int* __restrict__ ptr, const int* __restrict__ csrc,
               const float* __restrict__ cnrm, float* __restrict__ xg){
  __shared__ float zl[Nn*2];           // 32 KB
  int s = blockIdx.x;                  // t*32 + b
  int t = s >> 5, b = s & 31;
  int tid = threadIdx.x;
  const float* fb = feat + ((size_t)(b*TTC + t)*Nn)*9;
  const float* pb = pm25 + (size_t)(b*HISTC + t)*Nn;
  float sv[4][2];
  #pragma unroll
  for (int p=0;p<4;++p){
    int n = tid + p*1024;
    float x[10];
    x[0] = pb[n];
    #pragma unroll
    for (int f=0; f<9; ++f) x[1+f] = fb[(size_t)n*9+f];
    float z0=0.f, z1=0.f, s0=cb[0], s1=cb[1];
    #pragma unroll
    for (int f=0; f<10; ++f){
      s0 += x[f]*cw[f*2+0];      s1 += x[f]*cw[f*2+1];
      z0 += x[f]*cw[20+f*2+0];   z1 += x[f]*cw[20+f*2+1];
    }
    zl[n*2] = z0; zl[n*2+1] = z1;
    sv[p][0]=s0; sv[p][1]=s1;
  }
  __syncthreads();
  float* xgb = xg + (size_t)s*Nn*2;
  #pragma unroll
  for (int p=0;p<4;++p){
    int n = tid + p*1024;
    int p0 = ptr[n], p1 = ptr[n+1];
    float a0=sv[p][0], a1=sv[p][1];
    for (int i=p0;i<p1;++i){
      int si = csrc[i]; float w = cnrm[i];
      a0 += w*zl[si*2]; a1 += w*zl[si*2+1];
    }
    xgb[n*2]   = 1.f/(1.f+expf(-a0));
    xgb[n*2+1] = 1.f/(1.f+expf(-a1));
  }
}

// ---------------- fused z + gather : prediction (x0 from xn) ----------------
// 4 blocks per slice b; each computes full z slice into LDS (4x redundant),
// gathers for its own 1024 dst rows
__global__ __launch_bounds__(1024)
void k_xg_pred(const float* __restrict__ xn, const float* __restrict__ feat,
               const float* __restrict__ cw, const float* __restrict__ cb,
               const int* __restrict__ ptr, const int* __restrict__ csrc,
               const float* __restrict__ cnrm, float* __restrict__ xg, int t){
  __shared__ float zl[Nn*2];
  int bi = blockIdx.x;
  int b = bi >> 2, sub = bi & 3;
  int tid = threadIdx.x;
  const float* fb = feat + ((size_t)(b*TTC + t)*Nn)*9;
  const float* xb = xn + (size_t)b*Nn;
  float s0own=0.f, s1own=0.f;
  #pragma unroll
  for (int p=0;p<4;++p){
    int n = tid + p*1024;
    float x[10];
    x[0] = xb[n];
    #pragma unroll
    for (int f=0; f<9; ++f) x[1+f] = fb[(size_t)n*9+f];
    float z0=0.f, z1=0.f, s0=cb[0], s1=cb[1];
    #pragma unroll
    for (int f=0; f<10; ++f){
      s0 += x[f]*cw[f*2+0];      s1 += x[f]*cw[f*2+1];
      z0 += x[f]*cw[20+f*2+0];   z1 += x[f]*cw[20+f*2+1];
    }
    zl[n*2] = z0; zl[n*2+1] = z1;
    if (p == sub){ s0own = s0; s1own = s1; }
  }
  __syncthreads();
  int n = sub*1024 + tid;
  int p0 = ptr[n], p1 = ptr[n+1];
  float a0=s0own, a1=s1own;
  for (int i=p0;i<p1;++i){
    int si = csrc[i]; float w = cnrm[i];
    a0 += w*zl[si*2]; a1 += w*zl[si*2+1];
  }
  xg[((size_t)b*Nn+n)*2]   = 1.f/(1.f+expf(-a0));
  xg[((size_t)b*Nn+n)*2+1] = 1.f/(1.f+expf(-a1));
}

// ---------------- persistent history LSTM: all 16 steps in one kernel ----------------
// 256 thr = 64 rows x 4 thr/row; weights in LDS once; c in regs; h via LDS
__global__ __launch_bounds__(256,2)
void k_hist_steps(const float* __restrict__ pm25, const float* __restrict__ feat,
                  const float* __restrict__ xg,
                  const float* __restrict__ x2h_w, const float* __restrict__ x2h_b,
                  const float* __restrict__ h2h_w, const float* __restrict__ h2h_b,
                  const float* __restrict__ fc_w, const float* __restrict__ fc_b,
                  float* __restrict__ h, float* __restrict__ c, float* __restrict__ xn){
  __shared__ float s_wt[44*4*WT_STRIDE];
  __shared__ float s_b[128];
  __shared__ float s_gex[64*GEX_STRIDE];
  __shared__ float s_h[64*SH_STRIDE];
  int tid = threadIdx.x;
  for (int e = tid; e < 44*128; e += 256){
    int k = e >> 7, col = e & 127;
    int q = col >> 5, j = col & 31;
    float w = (k < 12) ? x2h_w[e] : h2h_w[e - 12*128];
    s_wt[(k*4+q)*WT_STRIDE + j] = w;
  }
  if (tid < 128) s_b[tid] = x2h_b[tid] + h2h_b[tid];
  for (int e = tid; e < 64*SH_STRIDE; e += 256) s_h[e] = 0.f;
  __syncthreads();

  int row = tid >> 2, q = tid & 3;
  int gr = blockIdx.x*64 + row;        // b*N + n
  int b = gr >> 12, n = gr & (Nn-1);
  const float* fb = feat + ((size_t)b*TTC*Nn + n)*9;   // + t*Nn*9
  const float* pb = pm25 + (size_t)b*HISTC*Nn + n;     // + t*Nn
  int u0 = q*8;

  float cc[8], hn[8];
  #pragma unroll
  for (int u=0;u<8;++u) cc[u]=0.f;

  float inv[12];
  inv[0] = pb[0];
  #pragma unroll
  for (int f=0;f<9;++f) inv[1+f] = fb[f];
  inv[10] = xg[(size_t)gr*2];
  inv[11] = xg[(size_t)gr*2+1];

  for (int t=0; t<HISTC; ++t){
    float acc[32];
    #pragma unroll
    for (int j=0;j<32;++j) acc[j] = s_b[q*32+j];
    #pragma unroll
    for (int k=0;k<12;++k){
      float v = inv[k];
      const float* wr = &s_wt[(k*4+q)*WT_STRIDE];
      #pragma unroll
      for (int j=0;j<32;++j) acc[j] += v*wr[j];
    }
    const float4* hp = (const float4*)&s_h[row*SH_STRIDE];
    #pragma unroll
    for (int v4=0; v4<8; ++v4){
      float4 h4 = hp[v4];
      float hv[4] = {h4.x, h4.y, h4.z, h4.w};
      #pragma unroll
      for (int kk=0;kk<4;++kk){
        float v = hv[kk];
        const float* wr = &s_wt[((12+4*v4+kk)*4+q)*WT_STRIDE];
        #pragma unroll
        for (int j=0;j<32;++j) acc[j] += v*wr[j];
      }
    }
    // prefetch next step's inputs while gates settle
    float nxt[12];
    if (t < HISTC-1){
      nxt[0] = pb[(size_t)(t+1)*Nn];
      #pragma unroll
      for (int f=0;f<9;++f) nxt[1+f] = fb[(size_t)(t+1)*Nn*9 + f];
      nxt[10] = xg[((size_t)(t+1)*BN + gr)*2];
      nxt[11] = xg[((size_t)(t+1)*BN + gr)*2+1];
    }
    {
      float* gx = &s_gex[row*GEX_STRIDE + q*36];
      #pragma unroll
      for (int j=0;j<32;++j) gx[j] = acc[j];
    }
    __syncthreads();
    const float* ge = &s_gex[row*GEX_STRIDE];
    #pragma unroll
    for (int u=0;u<8;++u){
      float iv = ge[0*36 + u0+u];
      float fv = ge[1*36 + u0+u];
      float gv = ge[2*36 + u0+u];
      float ov = ge[3*36 + u0+u];
      float ncc = sigm(fv)*cc[u] + sigm(iv)*tanhf(gv);
      cc[u] = ncc;
      hn[u] = sigm(ov)*tanhf(ncc);
    }
    #pragma unroll
    for (int u=0;u<8;++u) s_h[row*SH_STRIDE + u0+u] = hn[u];
    __syncthreads();
    if (t < HISTC-1){
      #pragma unroll
      for (int k=0;k<12;++k) inv[k] = nxt[k];
    }
  }

  // epilogue: persist h, c; xn = h @ fc + b
  float* cp = c + (size_t)gr*32 + u0;
  float* hq = h + (size_t)gr*32 + u0;
  #pragma unroll
  for (int u=0;u<8;++u){ cp[u]=cc[u]; hq[u]=hn[u]; }
  float part = 0.f;
  #pragma unroll
  for (int u=0;u<8;++u) part += hn[u]*fc_w[u0+u];
  part += __shfl_down(part, 2, 4);
  part += __shfl_down(part, 1, 4);
  if (q == 0) xn[gr] = part + fc_b[0];
}

// ---------------- one prediction LSTM step ----------------
__global__ __launch_bounds__(256,2)
void k_step_pred(const float* __restrict__ feat, const float* __restrict__ xg,
                 const float* __restrict__ x2h_w, const float* __restrict__ x2h_b,
                 const float* __restrict__ h2h_w, const float* __restrict__ h2h_b,
                 const float* __restrict__ fc_w, const float* __restrict__ fc_b,
                 float* __restrict__ h, float* __restrict__ c,
                 float* __restrict__ xn, float* __restrict__ out, int t){
  __shared__ float s_wt[44*4*WT_STRIDE];
  __shared__ float s_b[128];
  __shared__ float s_gex[64*GEX_STRIDE];
  int tid = threadIdx.x;
  for (int e = tid; e < 44*128; e += 256){
    int k = e >> 7, col = e & 127;
    int q = col >> 5, j = col & 31;
    float w = (k < 12) ? x2h_w[e] : h2h_w[e - 12*128];
    s_wt[(k*4+q)*WT_STRIDE + j] = w;
  }
  if (tid < 128) s_b[tid] = x2h_b[tid] + h2h_b[tid];
  __syncthreads();

  int row = tid >> 2, q = tid & 3;
  int gr = blockIdx.x*64 + row;
  int b = gr >> 12, n = gr & (Nn-1);

  float inv[12];
  inv[0] = xn[gr];
  const float* fp = feat + ((size_t)(b*TTC + t)*Nn + n)*9;
  #pragma unroll
  for (int f=0; f<9; ++f) inv[1+f] = fp[f];
  inv[10] = xg[(size_t)gr*2];
  inv[11] = xg[(size_t)gr*2+1];

  float acc[32];
  #pragma unroll
  for (int j=0; j<32; ++j) acc[j] = s_b[q*32+j];
  #pragma unroll
  for (int k=0; k<12; ++k){
    float v = inv[k];
    const float* wr = &s_wt[(k*4+q)*WT_STRIDE];
    #pragma unroll
    for (int j=0; j<32; ++j) acc[j] += v*wr[j];
  }
  const float4* hp = (const float4*)(h + (size_t)gr*32);
  #pragma unroll
  for (int v4=0; v4<8; ++v4){
    float4 h4 = hp[v4];
    float hvv[4] = {h4.x, h4.y, h4.z, h4.w};
    #pragma unroll
    for (int kk=0; kk<4; ++kk){
      float v = hvv[kk];
      const float* wr = &s_wt[((12+4*v4+kk)*4+q)*WT_STRIDE];
      #pragma unroll
      for (int j=0; j<32; ++j) acc[j] += v*wr[j];
    }
  }
  {
    float* gx = &s_gex[row*GEX_STRIDE + q*36];
    #pragma unroll
    for (int j=0; j<32; ++j) gx[j] = acc[j];
  }
  __syncthreads();
  int u0 = q*8;
  const float* ge = &s_gex[row*GEX_STRIDE];
  float* cp = c + (size_t)gr*32 + u0;
  float* hq = h + (size_t)gr*32 + u0;
  float hn[8];
  #pragma unroll
  for (int u=0; u<8; ++u){
    float iv = ge[0*36 + u0+u];
    float fv = ge[1*36 + u0+u];
    float gv = ge[2*36 + u0+u];
    float ov = ge[3*36 + u0+u];
    float ncc = sigm(fv)*cp[u] + sigm(iv)*tanhf(gv);
    cp[u] = ncc;
    hn[u] = sigm(ov)*tanhf(ncc);
  }
  #pragma unroll
  for (int u=0; u<8; ++u) hq[u] = hn[u];
  float part = 0.f;
  #pragma unroll
  for (int u=0; u<8; ++u) part += hn[u]*fc_w[u0+u];
  part += __shfl_down(part, 2, 4);
  part += __shfl_down(part, 1, 4);
  if (q == 0){
    float r = part + fc_b[0];
    xn[gr] = r;
    out[(size_t)b*PREDC*Nn + n] = r;     // out pre-offset by tp*Nn
  }
}

// ---------------- host ----------------
extern "C" void kernel_launch(void* const* d_in, const int* in_sizes, int n_in,
                              void* d_out, int out_size, void* d_ws, size_t ws_size,
                              hipStream_t stream){
  const float* pm25 = (const float*)d_in[0];
  const float* feat = (const float*)d_in[1];
  const int*   ei   = (const int*)d_in[2];
  const float* cw   = (const float*)d_in[3];
  const float* cb   = (const float*)d_in[4];
  const float* x2hw = (const float*)d_in[5];
  const float* x2hb = (const float*)d_in[6];
  const float* h2hw = (const float*)d_in[7];
  const float* h2hb = (const float*)d_in[8];
  const float* fcw  = (const float*)d_in[9];
  const float* fcb  = (const float*)d_in[10];
  float* out = (float*)d_out;

  char* w = (char*)d_ws;
  size_t off = 0;
  auto take = [&](size_t bytes)->char*{
    char* r = w + off; off += (bytes + 255) & ~(size_t)255; return r;
  };
  int*   deg   = (int*)  take(Nn*4);
  int*   cnt   = (int*)  take(Nn*4);
  int*   fillc = (int*)  take(Nn*4);
  int*   ptr   = (int*)  take((Nn+1)*4);
  float* dis   = (float*)take(Nn*4);
  int*   csrc  = (int*)  take(EC*4);
  float* cnrm  = (float*)take(EC*4);
  float* sbuf  = (float*)take((size_t)HISTC*BN*2*4);   // xg for hist; slice 0 reused for pred
  float* hbuf  = (float*)take((size_t)BN*32*4);
  float* cbuf  = (float*)take((size_t)BN*32*4);
  float* xnb   = (float*)take((size_t)BN*4);

  hipMemsetAsync(deg, 0, Nn*4*3, stream);              // deg,cnt,fillc adjacent

  k_deg<<<EC/256, 256, 0, stream>>>(ei, deg, cnt);
  k_dis<<<Nn/256, 256, 0, stream>>>(deg, dis);
  k_scan<<<1, 1024, 0, stream>>>(cnt, ptr);
  k_fill<<<EC/256, 256, 0, stream>>>(ei, dis, ptr, fillc, csrc, cnrm);

  // history: xg for all 16 steps (one block per (t,b) slice), then persistent LSTM
  k_xg_hist<<<HISTC*Bb, 1024, 0, stream>>>(pm25, feat, cw, cb, ptr, csrc, cnrm, sbuf);
  k_hist_steps<<<BN/64, 256, 0, stream>>>(pm25, feat, sbuf,
      x2hw, x2hb, h2hw, h2hb, fcw, fcb, hbuf, cbuf, xnb);

  for (int tp = 0; tp < PREDC; ++tp){
    int t = HISTC + tp;
    k_xg_pred<<<Bb*4, 1024, 0, stream>>>(xnb, feat, cw, cb, ptr, csrc, cnrm, sbuf, t);
    k_step_pred<<<BN/64, 256, 0, stream>>>(feat, sbuf,
        x2hw, x2hb, h2hw, h2hb, fcw, fcb, hbuf, cbuf, xnb, out + (size_t)tp*Nn, t);
  }
}

// Round 3
// 1846.107 us; speedup vs baseline: 11.5833x; 11.5833x over previous
//
#include <hip/hip_runtime.h>
#include <math.h>

#define Bb    32
#define Nn    4096
#define HISTC 16
#define PREDC 8
#define TTC   24
#define EC    65536
#define BN    (Bb*Nn)          // 131072

__device__ __forceinline__ float sigm_f(float x){
  return __builtin_amdgcn_rcpf(1.f + __expf(-x));
}
__device__ __forceinline__ float tanh_f(float x){
  // 1 - 2/(1+e^{2x}); saturates correctly at +-1 without clamps
  return fmaf(-2.f, __builtin_amdgcn_rcpf(1.f + __expf(2.f*x)), 1.f);
}

// ---------------- CSR build ----------------
__global__ void k_deg(const int* __restrict__ ei, int* deg, int* cnt){
  int e = blockIdx.x*blockDim.x + threadIdx.x;
  if (e < EC){ atomicAdd(&deg[ei[e]],1); atomicAdd(&cnt[ei[EC+e]],1); }
}
__global__ void k_dis(const int* __restrict__ deg, float* dis){
  int n = blockIdx.x*blockDim.x + threadIdx.x;
  if (n < Nn) dis[n] = deg[n] > 0 ? rsqrtf((float)deg[n]) : 0.f;
}
__global__ void k_scan(const int* __restrict__ cnt, int* ptr){
  __shared__ int sd[1024];
  int t = threadIdx.x;
  int c0=cnt[4*t], c1=cnt[4*t+1], c2=cnt[4*t+2], c3=cnt[4*t+3];
  int s = c0+c1+c2+c3;
  sd[t] = s; __syncthreads();
  for (int off=1; off<1024; off<<=1){
    int v = (t>=off) ? sd[t-off] : 0;
    __syncthreads();
    sd[t] += v;
    __syncthreads();
  }
  int excl = sd[t]-s;
  ptr[4*t]=excl; ptr[4*t+1]=excl+c0; ptr[4*t+2]=excl+c0+c1; ptr[4*t+3]=excl+c0+c1+c2;
  if (t==1023) ptr[4096]=sd[1023];
}
__global__ void k_fill(const int* __restrict__ ei, const float* __restrict__ dis,
                       const int* __restrict__ ptr, int* fillc, int* csrc, float* cnrm){
  int e = blockIdx.x*blockDim.x + threadIdx.x;
  if (e < EC){
    int s = ei[e], d = ei[EC+e];
    int pos = ptr[d] + atomicAdd(&fillc[d],1);
    csrc[pos] = s;
    cnrm[pos] = -dis[s]*dis[d];
  }
}
__global__ void k_bias(const float* __restrict__ x2hb, const float* __restrict__ h2hb,
                       float* __restrict__ bsum){
  int j = threadIdx.x;
  bsum[j] = x2hb[j] + h2hb[j];
}

// ---------------- fused z-compute + LDS gather + sigmoid : history ----------------
__global__ __launch_bounds__(1024)
void k_xg_hist(const float* __restrict__ pm25, const float* __restrict__ feat,
               const float* __restrict__ cw, const float* __restrict__ cb,
               const int* __restrict__ ptr, const int* __restrict__ csrc,
               const float* __restrict__ cnrm, float* __restrict__ xg){
  __shared__ float zl[Nn*2];           // 32 KB
  int s = blockIdx.x;                  // t*32 + b
  int t = s >> 5, b = s & 31;
  int tid = threadIdx.x;
  const float* fb = feat + ((size_t)(b*TTC + t)*Nn)*9;
  const float* pb = pm25 + (size_t)(b*HISTC + t)*Nn;
  float sv[4][2];
  #pragma unroll
  for (int p=0;p<4;++p){
    int n = tid + p*1024;
    float x[10];
    x[0] = pb[n];
    #pragma unroll
    for (int f=0; f<9; ++f) x[1+f] = fb[(size_t)n*9+f];
    float z0=0.f, z1=0.f, s0=cb[0], s1=cb[1];
    #pragma unroll
    for (int f=0; f<10; ++f){
      s0 += x[f]*cw[f*2+0];      s1 += x[f]*cw[f*2+1];
      z0 += x[f]*cw[20+f*2+0];   z1 += x[f]*cw[20+f*2+1];
    }
    zl[n*2] = z0; zl[n*2+1] = z1;
    sv[p][0]=s0; sv[p][1]=s1;
  }
  __syncthreads();
  float* xgb = xg + (size_t)s*Nn*2;
  #pragma unroll
  for (int p=0;p<4;++p){
    int n = tid + p*1024;
    int p0 = ptr[n], p1 = ptr[n+1];
    float a0=sv[p][0], a1=sv[p][1];
    for (int i=p0;i<p1;++i){
      int si = csrc[i]; float w = cnrm[i];
      a0 += w*zl[si*2]; a1 += w*zl[si*2+1];
    }
    xgb[n*2]   = sigm_f(a0);
    xgb[n*2+1] = sigm_f(a1);
  }
}

// ---------------- fused z + gather : prediction ----------------
__global__ __launch_bounds__(1024)
void k_xg_pred(const float* __restrict__ xn, const float* __restrict__ feat,
               const float* __restrict__ cw, const float* __restrict__ cb,
               const int* __restrict__ ptr, const int* __restrict__ csrc,
               const float* __restrict__ cnrm, float* __restrict__ xg, int t){
  __shared__ float zl[Nn*2];
  int bi = blockIdx.x;
  int b = bi >> 2, sub = bi & 3;
  int tid = threadIdx.x;
  const float* fb = feat + ((size_t)(b*TTC + t)*Nn)*9;
  const float* xb = xn + (size_t)b*Nn;
  float s0own=0.f, s1own=0.f;
  #pragma unroll
  for (int p=0;p<4;++p){
    int n = tid + p*1024;
    float x[10];
    x[0] = xb[n];
    #pragma unroll
    for (int f=0; f<9; ++f) x[1+f] = fb[(size_t)n*9+f];
    float z0=0.f, z1=0.f, s0=cb[0], s1=cb[1];
    #pragma unroll
    for (int f=0; f<10; ++f){
      s0 += x[f]*cw[f*2+0];      s1 += x[f]*cw[f*2+1];
      z0 += x[f]*cw[20+f*2+0];   z1 += x[f]*cw[20+f*2+1];
    }
    zl[n*2] = z0; zl[n*2+1] = z1;
    if (p == sub){ s0own = s0; s1own = s1; }
  }
  __syncthreads();
  int n = sub*1024 + tid;
  int p0 = ptr[n], p1 = ptr[n+1];
  float a0=s0own, a1=s1own;
  for (int i=p0;i<p1;++i){
    int si = csrc[i]; float w = cnrm[i];
    a0 += w*zl[si*2]; a1 += w*zl[si*2+1];
  }
  xg[((size_t)b*Nn+n)*2]   = sigm_f(a0);
  xg[((size_t)b*Nn+n)*2+1] = sigm_f(a1);
}

// ---------------- gate chunk: acc[u] = bsum + x@Wx + h@Wh for cols [JOFF,JOFF+32) ----
// All weight indices are wave-uniform compile-time offsets -> SMEM s_load stream;
// each lane owns one row -> pure v_fma on VALU, zero LDS.
template<int JOFF>
__device__ __forceinline__ void gate_chunk(const float* __restrict__ x2hw,
                                           const float* __restrict__ h2hw,
                                           const float* __restrict__ bsum,
                                           const float (&x)[12], const float (&h)[32],
                                           float (&acc)[32]){
  #pragma unroll
  for (int u=0;u<32;++u) acc[u] = bsum[JOFF+u];
  #pragma unroll
  for (int k=0;k<12;++k){
    float v = x[k];
    #pragma unroll
    for (int u=0;u<32;++u) acc[u] = fmaf(v, x2hw[k*128+JOFF+u], acc[u]);
  }
  #pragma unroll
  for (int k=0;k<32;++k){
    float v = h[k];
    #pragma unroll
    for (int u=0;u<32;++u) acc[u] = fmaf(v, h2hw[k*128+JOFF+u], acc[u]);
  }
}

// full LSTM cell on registers; gate order in g: [i f g o]
__device__ __forceinline__ void lstm_cell(const float* __restrict__ x2hw,
                                          const float* __restrict__ h2hw,
                                          const float* __restrict__ bsum,
                                          const float (&x)[12], float (&h)[32],
                                          float (&c)[32]){
  float accA[32], accB[32];
  gate_chunk<32>(x2hw, h2hw, bsum, x, h, accA);          // f gate
  #pragma unroll
  for (int u=0;u<32;++u) c[u] = c[u]*sigm_f(accA[u]);
  gate_chunk<0>(x2hw, h2hw, bsum, x, h, accA);           // i gate -> keep sigm in accA
  #pragma unroll
  for (int u=0;u<32;++u) accA[u] = sigm_f(accA[u]);
  gate_chunk<64>(x2hw, h2hw, bsum, x, h, accB);          // g gate
  #pragma unroll
  for (int u=0;u<32;++u) c[u] = fmaf(accA[u], tanh_f(accB[u]), c[u]);
  gate_chunk<96>(x2hw, h2hw, bsum, x, h, accA);          // o gate (last user of old h)
  #pragma unroll
  for (int u=0;u<32;++u) h[u] = sigm_f(accA[u])*tanh_f(c[u]);
}

// ---------------- persistent history LSTM: lane = row, 16 steps, regs only ------
__global__ __launch_bounds__(256,2)
void k_hist(const float* __restrict__ pm25, const float* __restrict__ feat,
            const float* __restrict__ xg,
            const float* __restrict__ x2hw, const float* __restrict__ h2hw,
            const float* __restrict__ bsum,
            const float* __restrict__ fcw, const float* __restrict__ fcb,
            float* __restrict__ hO, float* __restrict__ cO, float* __restrict__ xn){
  int gr = blockIdx.x*256 + threadIdx.x;     // b*N + n
  int b = gr >> 12, n = gr & (Nn-1);
  const float* fb = feat + ((size_t)b*TTC*Nn + n)*9;
  const float* pb = pm25 + (size_t)b*HISTC*Nn + n;

  float h[32], c[32];
  #pragma unroll
  for (int u=0;u<32;++u){ h[u]=0.f; c[u]=0.f; }

  for (int t=0; t<HISTC; ++t){
    float x[12];
    x[0] = pb[(size_t)t*Nn];
    #pragma unroll
    for (int f=0;f<9;++f) x[1+f] = fb[(size_t)t*Nn*9 + f];
    float2 xv = *(const float2*)&xg[((size_t)t*BN + gr)*2];
    x[10] = xv.x; x[11] = xv.y;
    lstm_cell(x2hw, h2hw, bsum, x, h, c);
  }

  float4* hp = (float4*)(hO + (size_t)gr*32);
  float4* cp = (float4*)(cO + (size_t)gr*32);
  #pragma unroll
  for (int v=0;v<8;++v){
    hp[v] = make_float4(h[4*v],h[4*v+1],h[4*v+2],h[4*v+3]);
    cp[v] = make_float4(c[4*v],c[4*v+1],c[4*v+2],c[4*v+3]);
  }
  float r = fcb[0];
  #pragma unroll
  for (int u=0;u<32;++u) r = fmaf(h[u], fcw[u], r);
  xn[gr] = r;
}

// ---------------- one prediction LSTM step (lane = row) ----------------
__global__ __launch_bounds__(256,2)
void k_pred_step(const float* __restrict__ feat, const float* __restrict__ xg,
                 const float* __restrict__ x2hw, const float* __restrict__ h2hw,
                 const float* __restrict__ bsum,
                 const float* __restrict__ fcw, const float* __restrict__ fcb,
                 float* __restrict__ hO, float* __restrict__ cO,
                 float* __restrict__ xn, float* __restrict__ out, int t){
  int gr = blockIdx.x*256 + threadIdx.x;
  int b = gr >> 12, n = gr & (Nn-1);

  float h[32], c[32];
  const float4* hp = (const float4*)(hO + (size_t)gr*32);
  const float4* cp = (const float4*)(cO + (size_t)gr*32);
  #pragma unroll
  for (int v=0;v<8;++v){
    float4 hv = hp[v]; h[4*v]=hv.x; h[4*v+1]=hv.y; h[4*v+2]=hv.z; h[4*v+3]=hv.w;
    float4 cv = cp[v]; c[4*v]=cv.x; c[4*v+1]=cv.y; c[4*v+2]=cv.z; c[4*v+3]=cv.w;
  }

  float x[12];
  x[0] = xn[gr];
  const float* fp = feat + ((size_t)(b*TTC + t)*Nn + n)*9;
  #pragma unroll
  for (int f=0;f<9;++f) x[1+f] = fp[f];
  float2 xv = *(const float2*)&xg[(size_t)gr*2];
  x[10] = xv.x; x[11] = xv.y;

  lstm_cell(x2hw, h2hw, bsum, x, h, c);

  float4* hw = (float4*)(hO + (size_t)gr*32);
  float4* cw2 = (float4*)(cO + (size_t)gr*32);
  #pragma unroll
  for (int v=0;v<8;++v){
    hw[v]  = make_float4(h[4*v],h[4*v+1],h[4*v+2],h[4*v+3]);
    cw2[v] = make_float4(c[4*v],c[4*v+1],c[4*v+2],c[4*v+3]);
  }
  float r = fcb[0];
  #pragma unroll
  for (int u=0;u<32;++u) r = fmaf(h[u], fcw[u], r);
  xn[gr] = r;
  out[(size_t)b*PREDC*Nn + n] = r;          // out pre-offset by tp*Nn
}

// ---------------- host ----------------
extern "C" void kernel_launch(void* const* d_in, const int* in_sizes, int n_in,
                              void* d_out, int out_size, void* d_ws, size_t ws_size,
                              hipStream_t stream){
  const float* pm25 = (const float*)d_in[0];
  const float* feat = (const float*)d_in[1];
  const int*   ei   = (const int*)d_in[2];
  const float* cw   = (const float*)d_in[3];
  const float* cb   = (const float*)d_in[4];
  const float* x2hw = (const float*)d_in[5];
  const float* x2hb = (const float*)d_in[6];
  const float* h2hw = (const float*)d_in[7];
  const float* h2hb = (const float*)d_in[8];
  const float* fcw  = (const float*)d_in[9];
  const float* fcb  = (const float*)d_in[10];
  float* out = (float*)d_out;

  char* w = (char*)d_ws;
  size_t off = 0;
  auto take = [&](size_t bytes)->char*{
    char* r = w + off; off += (bytes + 255) & ~(size_t)255; return r;
  };
  int*   deg   = (int*)  take(Nn*4);
  int*   cnt   = (int*)  take(Nn*4);
  int*   fillc = (int*)  take(Nn*4);
  int*   ptr   = (int*)  take((Nn+1)*4);
  float* dis   = (float*)take(Nn*4);
  int*   csrc  = (int*)  take(EC*4);
  float* cnrm  = (float*)take(EC*4);
  float* bsum  = (float*)take(128*4);
  float* sbuf  = (float*)take((size_t)HISTC*BN*2*4);   // xg hist; slice reused for pred
  float* hbuf  = (float*)take((size_t)BN*32*4);
  float* cbuf  = (float*)take((size_t)BN*32*4);
  float* xnb   = (float*)take((size_t)BN*4);

  hipMemsetAsync(deg, 0, Nn*4*3, stream);              // deg,cnt,fillc adjacent

  k_deg<<<EC/256, 256, 0, stream>>>(ei, deg, cnt);
  k_dis<<<Nn/256, 256, 0, stream>>>(deg, dis);
  k_scan<<<1, 1024, 0, stream>>>(cnt, ptr);
  k_fill<<<EC/256, 256, 0, stream>>>(ei, dis, ptr, fillc, csrc, cnrm);
  k_bias<<<1, 128, 0, stream>>>(x2hb, h2hb, bsum);

  k_xg_hist<<<HISTC*Bb, 1024, 0, stream>>>(pm25, feat, cw, cb, ptr, csrc, cnrm, sbuf);
  k_hist<<<BN/256, 256, 0, stream>>>(pm25, feat, sbuf, x2hw, h2hw, bsum,
                                     fcw, fcb, hbuf, cbuf, xnb);

  for (int tp = 0; tp < PREDC; ++tp){
    int t = HISTC + tp;
    k_xg_pred<<<Bb*4, 1024, 0, stream>>>(xnb, feat, cw, cb, ptr, csrc, cnrm, sbuf, t);
    k_pred_step<<<BN/256, 256, 0, stream>>>(feat, sbuf, x2hw, h2hw, bsum,
                                            fcw, fcb, hbuf, cbuf, xnb, out + (size_t)tp*Nn, t);
  }
}

// Round 5
// 1141.315 us; speedup vs baseline: 18.7363x; 1.6175x over previous
//
#include <hip/hip_runtime.h>
#include <math.h>

#define Bb    32
#define Nn    4096
#define HISTC 16
#define PREDC 8
#define TTC   24
#define EC    65536
#define BN    (Bb*Nn)          // 131072

typedef _Float16 h2f __attribute__((ext_vector_type(2)));
typedef __fp16  fp16v2 __attribute__((ext_vector_type(2)));

__device__ __forceinline__ float sigm_f(float x){
  return __builtin_amdgcn_rcpf(1.f + __expf(-x));
}
__device__ __forceinline__ float tanh_f(float x){
  return fmaf(-2.f, __builtin_amdgcn_rcpf(1.f + __expf(2.f*x)), 1.f);
}
__device__ __forceinline__ float fdot2f(unsigned a, unsigned b, float c){
#if __has_builtin(__builtin_amdgcn_fdot2)
  return __builtin_amdgcn_fdot2(__builtin_bit_cast(h2f, a),
                                __builtin_bit_cast(h2f, b), c, false);
#else
  h2f av = __builtin_bit_cast(h2f, a), bv = __builtin_bit_cast(h2f, b);
  return fmaf((float)av.x, (float)bv.x, fmaf((float)av.y, (float)bv.y, c));
#endif
}
__device__ __forceinline__ unsigned pk2(float a, float b){
#if __has_builtin(__builtin_amdgcn_cvt_pkrtz)
  fp16v2 v = __builtin_amdgcn_cvt_pkrtz(a, b);
  return __builtin_bit_cast(unsigned, v);
#else
  h2f v; v.x = (_Float16)a; v.y = (_Float16)b;
  return __builtin_bit_cast(unsigned, v);
#endif
}

// ---------------- CSR build ----------------
__global__ void k_deg(const int* __restrict__ ei, int* deg, int* cnt){
  int e = blockIdx.x*blockDim.x + threadIdx.x;
  if (e < EC){ atomicAdd(&deg[ei[e]],1); atomicAdd(&cnt[ei[EC+e]],1); }
}
__global__ void k_dis(const int* __restrict__ deg, float* dis){
  int n = blockIdx.x*blockDim.x + threadIdx.x;
  if (n < Nn) dis[n] = deg[n] > 0 ? rsqrtf((float)deg[n]) : 0.f;
}
__global__ void k_scan(const int* __restrict__ cnt, int* ptr){
  __shared__ int sd[1024];
  int t = threadIdx.x;
  int c0=cnt[4*t], c1=cnt[4*t+1], c2=cnt[4*t+2], c3=cnt[4*t+3];
  int s = c0+c1+c2+c3;
  sd[t] = s; __syncthreads();
  for (int off=1; off<1024; off<<=1){
    int v = (t>=off) ? sd[t-off] : 0;
    __syncthreads();
    sd[t] += v;
    __syncthreads();
  }
  int excl = sd[t]-s;
  ptr[4*t]=excl; ptr[4*t+1]=excl+c0; ptr[4*t+2]=excl+c0+c1; ptr[4*t+3]=excl+c0+c1+c2;
  if (t==1023) ptr[4096]=sd[1023];
}
__global__ void k_fill(const int* __restrict__ ei, const float* __restrict__ dis,
                       const int* __restrict__ ptr, int* fillc, int* csrc, float* cnrm){
  int e = blockIdx.x*blockDim.x + threadIdx.x;
  if (e < EC){
    int s = ei[e], d = ei[EC+e];
    int pos = ptr[d] + atomicAdd(&fillc[d],1);
    csrc[pos] = s;
    cnrm[pos] = -dis[s]*dis[d];
  }
}

// ---------------- pack weights to f16 k-pairs; fc pairs; bias sum ----------------
// wp[p][u]: pairs p=0..5 -> x2h rows (2p,2p+1); p=6..21 -> h2h rows (2p-12,2p-11)
__global__ void k_prep(const float* __restrict__ x2hw, const float* __restrict__ h2hw,
                       const float* __restrict__ x2hb, const float* __restrict__ h2hb,
                       const float* __restrict__ fcw,
                       unsigned* __restrict__ wp, unsigned* __restrict__ fcp,
                       float* __restrict__ bsum){
  int i = blockIdx.x*256 + threadIdx.x;
  if (i < 2816){
    int p = i >> 7, u = i & 127;
    float lo, hi;
    if (p < 6){ lo = x2hw[(2*p)*128+u];    hi = x2hw[(2*p+1)*128+u]; }
    else      { lo = h2hw[(2*p-12)*128+u]; hi = h2hw[(2*p-11)*128+u]; }
    wp[i] = pk2(lo, hi);
  } else if (i < 2832){
    int j = i - 2816;
    fcp[j] = pk2(fcw[2*j], fcw[2*j+1]);
  } else if (i < 2960){
    int j = i - 2832;
    bsum[j] = x2hb[j] + h2hb[j];
  }
}

// ---------------- fused z-compute + LDS gather + sigmoid : history xg ----------------
__global__ __launch_bounds__(1024)
void k_xg_hist(const float* __restrict__ pm25, const float* __restrict__ feat,
               const float* __restrict__ cw, const float* __restrict__ cb,
               const int* __restrict__ ptr, const int* __restrict__ csrc,
               const float* __restrict__ cnrm, float* __restrict__ xg){
  __shared__ float zl[Nn*2];           // 32 KB
  int s = blockIdx.x;                  // t*32 + b
  int t = s >> 5, b = s & 31;
  int tid = threadIdx.x;
  const float* fb = feat + ((size_t)(b*TTC + t)*Nn)*9;
  const float* pb = pm25 + (size_t)(b*HISTC + t)*Nn;
  float sv[4][2];
  #pragma unroll
  for (int p=0;p<4;++p){
    int n = tid + p*1024;
    float x[10];
    x[0] = pb[n];
    #pragma unroll
    for (int f=0; f<9; ++f) x[1+f] = fb[(size_t)n*9+f];
    float z0=0.f, z1=0.f, s0=cb[0], s1=cb[1];
    #pragma unroll
    for (int f=0; f<10; ++f){
      s0 += x[f]*cw[f*2+0];      s1 += x[f]*cw[f*2+1];
      z0 += x[f]*cw[20+f*2+0];   z1 += x[f]*cw[20+f*2+1];
    }
    zl[n*2] = z0; zl[n*2+1] = z1;
    sv[p][0]=s0; sv[p][1]=s1;
  }
  __syncthreads();
  float* xgb = xg + (size_t)s*Nn*2;
  #pragma unroll
  for (int p=0;p<4;++p){
    int n = tid + p*1024;
    int p0 = ptr[n], p1 = ptr[n+1];
    float a0=sv[p][0], a1=sv[p][1];
    for (int i=p0;i<p1;++i){
      int si = csrc[i]; float w = cnrm[i];
      a0 += w*zl[si*2]; a1 += w*zl[si*2+1];
    }
    xgb[n*2]   = sigm_f(a0);
    xgb[n*2+1] = sigm_f(a1);
  }
}

// ---------------- gate chunk via v_dot2_f32_f16; weights stream on SMEM ----------
template<int JOFF>
__device__ __forceinline__ void gate4(const unsigned* __restrict__ wp,
                                      const float* __restrict__ bsum,
                                      const unsigned (&pk)[22], float (&acc)[32]){
  #pragma unroll
  for (int u=0;u<32;++u) acc[u] = bsum[JOFF+u];
  #pragma unroll
  for (int p=0;p<22;++p){
    unsigned xv = pk[p];
    #pragma unroll
    for (int u=0;u<32;++u) acc[u] = fdot2f(xv, wp[p*128+JOFF+u], acc[u]);
  }
}

// full cell; pk[0..5]=x pairs (in), pk[6..21]=h pairs (in/out); c f32 (in/out)
__device__ __forceinline__ void cell(const unsigned* __restrict__ wp,
                                     const float* __restrict__ bsum,
                                     unsigned (&pk)[22], float (&c)[32]){
  float acc[32], si[32];
  gate4<32>(wp, bsum, pk, acc);                 // f
  #pragma unroll
  for (int u=0;u<32;++u) c[u] *= sigm_f(acc[u]);
  gate4<0>(wp, bsum, pk, acc);                  // i
  #pragma unroll
  for (int u=0;u<32;++u) si[u] = sigm_f(acc[u]);
  gate4<64>(wp, bsum, pk, acc);                 // g
  #pragma unroll
  for (int u=0;u<32;++u) c[u] = fmaf(si[u], tanh_f(acc[u]), c[u]);
  gate4<96>(wp, bsum, pk, acc);                 // o
  #pragma unroll
  for (int u=0;u<32;++u) si[u] = sigm_f(acc[u])*tanh_f(c[u]);   // new h (f32)
  #pragma unroll
  for (int j=0;j<16;++j) pk[6+j] = pk2(si[2*j], si[2*j+1]);
}

// ---------------- persistent history LSTM: lane = row, 16 steps in-register -----
__global__ __launch_bounds__(256,1)
void k_hist(const float* __restrict__ pm25, const float* __restrict__ feat,
            const float* __restrict__ xg,
            const unsigned* __restrict__ wp, const float* __restrict__ bsum,
            const unsigned* __restrict__ fcp, const float* __restrict__ fcb,
            unsigned* __restrict__ hpO, float* __restrict__ cO, float* __restrict__ xn0){
  size_t gr = blockIdx.x*256 + threadIdx.x;     // b*N + n
  int b = (int)(gr >> 12), n = (int)(gr & (Nn-1));
  const float* fb = feat + ((size_t)b*TTC*Nn + n)*9;
  const float* pb = pm25 + (size_t)b*HISTC*Nn + n;

  unsigned pk[22];
  float c[32];
  #pragma unroll
  for (int j=0;j<16;++j) pk[6+j] = 0u;          // h = 0
  #pragma unroll
  for (int u=0;u<32;++u) c[u] = 0.f;

  float xf[12];
  xf[0] = pb[0];
  #pragma unroll
  for (int f=0;f<9;++f) xf[1+f] = fb[f];
  { float2 g = *(const float2*)&xg[gr*2]; xf[10]=g.x; xf[11]=g.y; }

  #pragma unroll 1
  for (int t=0; t<HISTC; ++t){
    #pragma unroll
    for (int j=0;j<6;++j) pk[j] = pk2(xf[2*j], xf[2*j+1]);
    if (t < HISTC-1){                           // prefetch next step's x
      xf[0] = pb[(size_t)(t+1)*Nn];
      #pragma unroll
      for (int f=0;f<9;++f) xf[1+f] = fb[(size_t)(t+1)*Nn*9 + f];
      float2 g = *(const float2*)&xg[((size_t)(t+1)*BN + gr)*2];
      xf[10]=g.x; xf[11]=g.y;
    }
    cell(wp, bsum, pk, c);
  }

  uint4* hp = (uint4*)(hpO + gr*16);
  #pragma unroll
  for (int v=0;v<4;++v) hp[v] = make_uint4(pk[6+4*v],pk[7+4*v],pk[8+4*v],pk[9+4*v]);
  float4* cp = (float4*)(cO + gr*32);
  #pragma unroll
  for (int v=0;v<8;++v) cp[v] = make_float4(c[4*v],c[4*v+1],c[4*v+2],c[4*v+3]);
  float r = fcb[0];
  #pragma unroll
  for (int j=0;j<16;++j) r = fdot2f(pk[6+j], fcp[j], r);
  xn0[gr] = r;
}

// ---------------- fused pred step: z in LDS + gather + LSTM + fc ----------------
// 512 blocks: b = blk&31, sub = blk>>5
__global__ __launch_bounds__(256,1)
void k_pred(const float* __restrict__ feat, const float* __restrict__ xnI,
            const float* __restrict__ cw, const float* __restrict__ cb,
            const int* __restrict__ ptr, const int* __restrict__ csrc,
            const float* __restrict__ cnrm,
            const unsigned* __restrict__ wp, const float* __restrict__ bsum,
            const unsigned* __restrict__ fcp, const float* __restrict__ fcb,
            unsigned* __restrict__ hpO, float* __restrict__ cO,
            float* __restrict__ xnO, float* __restrict__ out, int t){
  __shared__ float zl[Nn*2];                    // 32 KB
  int blk = blockIdx.x;
  int b = blk & 31, sub = blk >> 5;
  int tid = threadIdx.x;
  const float* fb = feat + ((size_t)(b*TTC + t)*Nn)*9;
  const float* xb = xnI + (size_t)b*Nn;

  float xf[10]; float sown0=0.f, sown1=0.f;
  #pragma unroll 1
  for (int p=0;p<16;++p){
    int n = p*256 + tid;
    float x[10];
    x[0] = xb[n];
    #pragma unroll
    for (int f=0;f<9;++f) x[1+f] = fb[(size_t)n*9+f];
    float z0=0.f, z1=0.f, s0=cb[0], s1=cb[1];
    #pragma unroll
    for (int f=0;f<10;++f){
      s0 += x[f]*cw[f*2+0];      s1 += x[f]*cw[f*2+1];
      z0 += x[f]*cw[20+f*2+0];   z1 += x[f]*cw[20+f*2+1];
    }
    zl[n*2] = z0; zl[n*2+1] = z1;
    if (p == sub){
      sown0 = s0; sown1 = s1;
      #pragma unroll
      for (int f=0;f<10;++f) xf[f] = x[f];
    }
  }
  __syncthreads();

  int n = sub*256 + tid;
  size_t gr = (size_t)b*Nn + n;
  int p0 = ptr[n], p1 = ptr[n+1];
  float a0 = sown0, a1 = sown1;
  for (int i=p0;i<p1;++i){
    int si = csrc[i]; float w = cnrm[i];
    a0 += w*zl[si*2]; a1 += w*zl[si*2+1];
  }
  float xg0 = sigm_f(a0), xg1 = sigm_f(a1);

  unsigned pk[22];
  #pragma unroll
  for (int j=0;j<5;++j) pk[j] = pk2(xf[2*j], xf[2*j+1]);
  pk[5] = pk2(xg0, xg1);
  const uint4* hpI = (const uint4*)(hpO + gr*16);
  #pragma unroll
  for (int v=0;v<4;++v){
    uint4 hv = hpI[v];
    pk[6+4*v]=hv.x; pk[7+4*v]=hv.y; pk[8+4*v]=hv.z; pk[9+4*v]=hv.w;
  }
  float c[32];
  const float4* cI = (const float4*)(cO + gr*32);
  #pragma unroll
  for (int v=0;v<8;++v){
    float4 cv = cI[v]; c[4*v]=cv.x; c[4*v+1]=cv.y; c[4*v+2]=cv.z; c[4*v+3]=cv.w;
  }

  cell(wp, bsum, pk, c);

  uint4* hp = (uint4*)(hpO + gr*16);
  #pragma unroll
  for (int v=0;v<4;++v) hp[v] = make_uint4(pk[6+4*v],pk[7+4*v],pk[8+4*v],pk[9+4*v]);
  float4* cp = (float4*)(cO + gr*32);
  #pragma unroll
  for (int v=0;v<8;++v) cp[v] = make_float4(c[4*v],c[4*v+1],c[4*v+2],c[4*v+3]);
  float r = fcb[0];
  #pragma unroll
  for (int j=0;j<16;++j) r = fdot2f(pk[6+j], fcp[j], r);
  xnO[gr] = r;
  out[(size_t)b*PREDC*Nn + n] = r;              // out pre-offset by tp*Nn
}

// ---------------- host ----------------
extern "C" void kernel_launch(void* const* d_in, const int* in_sizes, int n_in,
                              void* d_out, int out_size, void* d_ws, size_t ws_size,
                              hipStream_t stream){
  const float* pm25 = (const float*)d_in[0];
  const float* feat = (const float*)d_in[1];
  const int*   ei   = (const int*)d_in[2];
  const float* cw   = (const float*)d_in[3];
  const float* cb   = (const float*)d_in[4];
  const float* x2hw = (const float*)d_in[5];
  const float* x2hb = (const float*)d_in[6];
  const float* h2hw = (const float*)d_in[7];
  const float* h2hb = (const float*)d_in[8];
  const float* fcw  = (const float*)d_in[9];
  const float* fcb  = (const float*)d_in[10];
  float* out = (float*)d_out;

  char* w = (char*)d_ws;
  size_t off = 0;
  auto take = [&](size_t bytes)->char*{
    char* r = w + off; off += (bytes + 255) & ~(size_t)255; return r;
  };
  int*      deg   = (int*)     take(Nn*4);
  int*      cnt   = (int*)     take(Nn*4);
  int*      fillc = (int*)     take(Nn*4);
  int*      ptr   = (int*)     take((Nn+1)*4);
  float*    dis   = (float*)   take(Nn*4);
  int*      csrc  = (int*)     take(EC*4);
  float*    cnrm  = (float*)   take(EC*4);
  unsigned* wpB   = (unsigned*)take(2816*4);
  unsigned* fcp   = (unsigned*)take(16*4);
  float*    bsum  = (float*)   take(128*4);
  float*    sbuf  = (float*)   take((size_t)HISTC*BN*2*4);   // hist xg
  unsigned* hpB   = (unsigned*)take((size_t)BN*16*4);        // packed f16 h
  float*    cbuf  = (float*)   take((size_t)BN*32*4);
  float*    xn0   = (float*)   take((size_t)BN*4);
  float*    xn1   = (float*)   take((size_t)BN*4);

  (void)hipMemsetAsync(deg, 0, Nn*4*3, stream);  // deg,cnt,fillc adjacent

  k_deg <<<EC/256, 256, 0, stream>>>(ei, deg, cnt);
  k_dis <<<Nn/256, 256, 0, stream>>>(deg, dis);
  k_scan<<<1, 1024, 0, stream>>>(cnt, ptr);
  k_fill<<<EC/256, 256, 0, stream>>>(ei, dis, ptr, fillc, csrc, cnrm);
  k_prep<<<12, 256, 0, stream>>>(x2hw, h2hw, x2hb, h2hb, fcw, wpB, fcp, bsum);

  k_xg_hist<<<HISTC*Bb, 1024, 0, stream>>>(pm25, feat, cw, cb, ptr, csrc, cnrm, sbuf);
  k_hist<<<BN/256, 256, 0, stream>>>(pm25, feat, sbuf, wpB, bsum, fcp, fcb,
                                     hpB, cbuf, xn0);

  for (int tp = 0; tp < PREDC; ++tp){
    int t = HISTC + tp;
    float* xi = (tp & 1) ? xn1 : xn0;
    float* xo = (tp & 1) ? xn0 : xn1;
    k_pred<<<Bb*16, 256, 0, stream>>>(feat, xi, cw, cb, ptr, csrc, cnrm,
                                      wpB, bsum, fcp, fcb, hpB, cbuf,
                                      xo, out + (size_t)tp*Nn, t);
  }
}